// Round 4
// baseline (1793.819 us; speedup 1.0000x reference)
//
#include <hip/hip_runtime.h>
#include <hip/hip_bf16.h>

#define CDIV(a,b) (((a)+(b)-1)/(b))

typedef __attribute__((ext_vector_type(8))) short s8v;   // 8 x bf16 bits
typedef __attribute__((ext_vector_type(4))) float f4v;   // MFMA acc

static __device__ __forceinline__ unsigned short f2bf(float f) {
  unsigned int u = __float_as_uint(f);
  u += 0x7fffu + ((u >> 16) & 1u);           // round-nearest-even
  return (unsigned short)(u >> 16);
}
static __device__ __forceinline__ float bfbits2f(unsigned int b) {
  return __uint_as_float(b << 16);
}

// ---------------- weight preprocessing ----------------
// w1 [3][128][512] f32 -> w1t [3][512][128] bf16 (n-major, k contiguous)
__global__ void k_w1t(const float* __restrict__ w1, unsigned short* __restrict__ w1t) {
  int idx = blockIdx.x * 256 + threadIdx.x;
  if (idx >= 3 * 512 * 128) return;
  int p = idx >> 16;
  int rem = idx & 65535;
  int n = rem >> 7, k = rem & 127;
  w1t[idx] = f2bf(w1[p * 65536 + k * 512 + n]);
}

// w2 [2][1536][40] f32 -> w2t [80][1536] bf16; col j<40 from w2[0], j>=40 from w2[1]
__global__ void k_w2t(const float* __restrict__ w2, unsigned short* __restrict__ w2t) {
  int idx = blockIdx.x * 256 + threadIdx.x;
  if (idx >= 80 * 1536) return;
  int j = idx / 1536, k = idx % 1536;
  int g  = (j < 40) ? 0 : 1;
  int jj = (j < 40) ? j : j - 40;
  w2t[idx] = f2bf(w2[g * 61440 + k * 40 + jj]);
}

// s0 = dinv ⊙ x  -> bf16, float4 granularity (32 float4 per row)
__global__ void k_cvts(const float* __restrict__ src, const float* __restrict__ dinv,
                       unsigned short* __restrict__ dst, int n4) {
  int i = blockIdx.x * 256 + threadIdx.x;
  if (i >= n4) return;
  float d = dinv[i >> 5];
  float4 v = ((const float4*)src)[i];
  ushort4 o;
  o.x = f2bf(d * v.x); o.y = f2bf(d * v.y); o.z = f2bf(d * v.z); o.w = f2bf(d * v.w);
  ((ushort4*)dst)[i] = o;
}

// ---------------- CSR build ----------------
__global__ void k_zero(int* __restrict__ a, int n) {
  int i = blockIdx.x * 256 + threadIdx.x;
  if (i < n) a[i] = 0;
}
__global__ void k_cnt(const int* __restrict__ col, int* __restrict__ cnt, int E) {
  int i = blockIdx.x * 256 + threadIdx.x;
  if (i < E) atomicAdd(&cnt[col[i]], 1);
}
// dinv = rsqrt(deg), rdeg = sqrt(deg), deg = cnt+1 (self loop)
__global__ void k_dinv(const int* __restrict__ cnt, float* __restrict__ dinv,
                       float* __restrict__ rdeg, int n) {
  int i = blockIdx.x * 256 + threadIdx.x;
  if (i >= n) return;
  float deg = (float)(cnt[i] + 1);
  dinv[i] = rsqrtf(deg);
  rdeg[i] = sqrtf(deg);
}

// exclusive scan of cnt[N] -> off[N] (partial within 256-block) + blockSum
__global__ void k_scan1(const int* __restrict__ cnt, int* __restrict__ off,
                        int* __restrict__ blockSum, int N) {
  __shared__ int s[256];
  int t = threadIdx.x, idx = blockIdx.x * 256 + t;
  int val = (idx < N) ? cnt[idx] : 0;
  s[t] = val;
  __syncthreads();
  for (int d = 1; d < 256; d <<= 1) {
    int add = (t >= d) ? s[t - d] : 0;
    __syncthreads();
    s[t] += add;
    __syncthreads();
  }
  if (idx < N) off[idx] = s[t] - val;
  if (t == 255) blockSum[blockIdx.x] = s[255];
}
__global__ void k_scan2(const int* __restrict__ blockSum, int* __restrict__ blockOff,
                        int* __restrict__ off, int NB, int N) {
  __shared__ int s[1024];
  int t = threadIdx.x;
  int val = (t < NB) ? blockSum[t] : 0;
  s[t] = val;
  __syncthreads();
  for (int d = 1; d < 1024; d <<= 1) {
    int add = (t >= d) ? s[t - d] : 0;
    __syncthreads();
    s[t] += add;
    __syncthreads();
  }
  blockOff[t] = s[t] - val;
  if (t == 1023) off[N] = s[1023];
}
__global__ void k_scan3(int* __restrict__ off, const int* __restrict__ blockOff,
                        int* __restrict__ cursor, int N) {
  int i = blockIdx.x * 256 + threadIdx.x;
  if (i >= N) return;
  int o = off[i] + blockOff[i >> 8];
  off[i] = o;
  cursor[i] = o;
}
// scatter edge source rows into buckets sorted by destination col (single 4B write)
__global__ void k_scatter(const int* __restrict__ row, const int* __restrict__ col,
                          int* __restrict__ cursor, int* __restrict__ rows, int E) {
  int e = blockIdx.x * 256 + threadIdx.x;
  if (e >= E) return;
  int pos = atomicAdd(&cursor[col[e]], 1);
  rows[pos] = row[e];
}

// ---------------- SpMM gather (scaled features, unweighted sums) ----------------
// s_out[c] = dinv[c]^2 * (s_in[c] + sum_e s_in[r_e]); width 128 bf16, wave/node
__global__ __launch_bounds__(256) void k_gather128(
    const unsigned short* __restrict__ src, const int* __restrict__ off,
    const int* __restrict__ rows, const float* __restrict__ dinv,
    unsigned short* __restrict__ dst, int N) {
  int c = blockIdx.x * 4 + (threadIdx.x >> 6);
  if (c >= N) return;
  int lane = threadIdx.x & 63;
  const int b = off[c], e = off[c + 1];
  unsigned int sv = *(const unsigned int*)(src + (size_t)c * 128 + lane * 2);
  float a0 = bfbits2f(sv & 0xffffu);
  float a1 = bfbits2f(sv >> 16);
  int k = b;
  for (; k + 4 <= e; k += 4) {
    int r0 = rows[k], r1 = rows[k + 1], r2 = rows[k + 2], r3 = rows[k + 3];
    unsigned int v0 = *(const unsigned int*)(src + (size_t)r0 * 128 + lane * 2);
    unsigned int v1 = *(const unsigned int*)(src + (size_t)r1 * 128 + lane * 2);
    unsigned int v2 = *(const unsigned int*)(src + (size_t)r2 * 128 + lane * 2);
    unsigned int v3 = *(const unsigned int*)(src + (size_t)r3 * 128 + lane * 2);
    a0 += bfbits2f(v0 & 0xffffu) + bfbits2f(v1 & 0xffffu)
        + bfbits2f(v2 & 0xffffu) + bfbits2f(v3 & 0xffffu);
    a1 += bfbits2f(v0 >> 16) + bfbits2f(v1 >> 16)
        + bfbits2f(v2 >> 16) + bfbits2f(v3 >> 16);
  }
  for (; k < e; ++k) {
    unsigned int v0 = *(const unsigned int*)(src + (size_t)rows[k] * 128 + lane * 2);
    a0 += bfbits2f(v0 & 0xffffu);
    a1 += bfbits2f(v0 >> 16);
  }
  float d = dinv[c], dd = d * d;
  unsigned int o = (unsigned int)f2bf(dd * a0) | ((unsigned int)f2bf(dd * a1) << 16);
  *(unsigned int*)(dst + (size_t)c * 128 + lane * 2) = o;
}

// u1[c] = dinv[c] * (t1s[c] + sum_e t1s[r_e]); width 40 f32, wave/node
__global__ __launch_bounds__(256) void k_gather40(
    const float* __restrict__ src, const int* __restrict__ off,
    const int* __restrict__ rows, const float* __restrict__ dinv,
    float* __restrict__ dst, int N) {
  int c = blockIdx.x * 4 + (threadIdx.x >> 6);
  if (c >= N) return;
  int lane = threadIdx.x & 63;
  if (lane >= 40) return;
  const int b = off[c], e = off[c + 1];
  float acc = src[(size_t)c * 40 + lane];
  int k = b;
  for (; k + 2 <= e; k += 2) {
    int r0 = rows[k], r1 = rows[k + 1];
    acc += src[(size_t)r0 * 40 + lane] + src[(size_t)r1 * 40 + lane];
  }
  if (k < e) acc += src[(size_t)rows[k] * 40 + lane];
  dst[(size_t)c * 40 + lane] = dinv[c] * acc;
}

// ---------------- GEMM 1: H[:,col0:+512] = relu(rdeg[row] * (S[M,128] @ B) + b1) ----------------
// block 256 thr (4 waves), 64 rows; wave w owns cols [w*128, +128)
__global__ __launch_bounds__(256) void k_gemm1(
    const unsigned short* __restrict__ A, const unsigned short* __restrict__ Bt,
    const float* __restrict__ rdeg, const float* __restrict__ bias,
    unsigned short* __restrict__ H, int M, int col0) {
  const int tid = threadIdx.x, wave = tid >> 6, lane = tid & 63;
  const int lhi = lane >> 4, llo = lane & 15;
  const int row0 = blockIdx.x * 64;
  f4v acc[4][8];
#pragma unroll
  for (int i = 0; i < 4; ++i)
#pragma unroll
    for (int j = 0; j < 8; ++j) acc[i][j] = (f4v){0.f, 0.f, 0.f, 0.f};
  size_t arow[4];
#pragma unroll
  for (int i = 0; i < 4; ++i) {
    int r = row0 + i * 16 + llo; if (r > M - 1) r = M - 1;
    arow[i] = (size_t)r * 128 + lhi * 8;
  }
  const unsigned short* Bw = Bt + (size_t)(wave * 128 + llo) * 128 + lhi * 8;
#pragma unroll
  for (int kk = 0; kk < 128; kk += 32) {
    s8v a[4], b[8];
#pragma unroll
    for (int i = 0; i < 4; ++i) a[i] = *(const s8v*)(A + arow[i] + kk);
#pragma unroll
    for (int j = 0; j < 8; ++j) b[j] = *(const s8v*)(Bw + (size_t)j * 16 * 128 + kk);
#pragma unroll
    for (int i = 0; i < 4; ++i)
#pragma unroll
      for (int j = 0; j < 8; ++j)
        acc[i][j] = __builtin_amdgcn_mfma_f32_16x16x32_bf16(a[i], b[j], acc[i][j], 0, 0, 0);
  }
  float scr[4][4];
#pragma unroll
  for (int i = 0; i < 4; ++i)
#pragma unroll
    for (int r = 0; r < 4; ++r) {
      int rowg = row0 + i * 16 + lhi * 4 + r;
      scr[i][r] = (rowg < M) ? rdeg[rowg] : 0.f;
    }
#pragma unroll
  for (int i = 0; i < 4; ++i) {
#pragma unroll
    for (int j = 0; j < 8; ++j) {
      int colg = col0 + wave * 128 + j * 16 + llo;
      float bv = bias[colg];
#pragma unroll
      for (int r = 0; r < 4; ++r) {
        int rowg = row0 + i * 16 + lhi * 4 + r;
        if (rowg < M) {
          float v = acc[i][j][r] * scr[i][r] + bv;
          H[(size_t)rowg * 1536 + colg] = f2bf(v > 0.f ? v : 0.f);
        }
      }
    }
  }
}

// ---------------- GEMM 2: [M,1536]bf16 @ [1536,80] -> t0(+b2) into out[:,0:40], t1s = dinv*t1 ----------------
__global__ __launch_bounds__(256) void k_gemm2(
    const unsigned short* __restrict__ Hm, const unsigned short* __restrict__ Bt,
    const float* __restrict__ b2, const float* __restrict__ dinv,
    float* __restrict__ out, float* __restrict__ t1s, int M) {
  const int tid = threadIdx.x, wave = tid >> 6, lane = tid & 63;
  const int lhi = lane >> 4, llo = lane & 15;
  const int row0 = blockIdx.x * 256 + wave * 64;
  f4v acc[4][5];
#pragma unroll
  for (int i = 0; i < 4; ++i)
#pragma unroll
    for (int j = 0; j < 5; ++j) acc[i][j] = (f4v){0.f, 0.f, 0.f, 0.f};
  size_t arow[4];
#pragma unroll
  for (int i = 0; i < 4; ++i) {
    int r = row0 + i * 16 + llo; if (r > M - 1) r = M - 1;
    arow[i] = (size_t)r * 1536 + lhi * 8;
  }
  const unsigned short* Bw = Bt + (size_t)llo * 1536 + lhi * 8;
  for (int kk = 0; kk < 1536; kk += 32) {
    s8v a[4], b[5];
#pragma unroll
    for (int i = 0; i < 4; ++i) a[i] = *(const s8v*)(Hm + arow[i] + kk);
#pragma unroll
    for (int j = 0; j < 5; ++j) b[j] = *(const s8v*)(Bw + (size_t)j * 16 * 1536 + kk);
#pragma unroll
    for (int i = 0; i < 4; ++i)
#pragma unroll
      for (int j = 0; j < 5; ++j)
        acc[i][j] = __builtin_amdgcn_mfma_f32_16x16x32_bf16(a[i], b[j], acc[i][j], 0, 0, 0);
  }
  float dv[4][4];
#pragma unroll
  for (int i = 0; i < 4; ++i)
#pragma unroll
    for (int r = 0; r < 4; ++r) {
      int rowg = row0 + i * 16 + lhi * 4 + r;
      dv[i][r] = (rowg < M) ? dinv[rowg] : 0.f;
    }
#pragma unroll
  for (int i = 0; i < 4; ++i)
#pragma unroll
    for (int j = 0; j < 5; ++j) {
      int col = j * 16 + llo;
#pragma unroll
      for (int r = 0; r < 4; ++r) {
        int rowg = row0 + i * 16 + lhi * 4 + r;
        if (rowg < M) {
          float v = acc[i][j][r];
          if (col < 40) out[(size_t)rowg * 80 + col] = v + b2[col];
          else          t1s[(size_t)rowg * 40 + col - 40] = dv[i][r] * v;
        }
      }
    }
}

// ---------------- log_softmax over 80 cols; one wave per row ----------------
__global__ void k_logsm(float* __restrict__ out, const float* __restrict__ u1,
                        const float* __restrict__ b2, int N) {
  int n = blockIdx.x * 4 + (threadIdx.x >> 6);
  if (n >= N) return;
  int lane = threadIdx.x & 63;
  float v0, v1;
  if (lane < 40) v0 = out[(size_t)n * 80 + lane];
  else           v0 = u1[(size_t)n * 40 + lane - 40] + b2[lane];
  v1 = (lane < 16) ? (u1[(size_t)n * 40 + 24 + lane] + b2[64 + lane]) : -INFINITY;
  float m = fmaxf(v0, v1);
#pragma unroll
  for (int s = 32; s > 0; s >>= 1) m = fmaxf(m, __shfl_xor(m, s));
  float s = __expf(v0 - m) + ((lane < 16) ? __expf(v1 - m) : 0.f);
#pragma unroll
  for (int sft = 32; sft > 0; sft >>= 1) s += __shfl_xor(s, sft);
  float L = m + __logf(s);
  out[(size_t)n * 80 + lane] = v0 - L;
  if (lane < 16) out[(size_t)n * 80 + 64 + lane] = v1 - L;
}

// ---------------- launch ----------------
extern "C" void kernel_launch(void* const* d_in, const int* in_sizes, int n_in,
                              void* d_out, int out_size, void* d_ws, size_t ws_size,
                              hipStream_t stream) {
  const float* x  = (const float*)d_in[0];
  const int*   ei = (const int*)d_in[1];
  const float* w1 = (const float*)d_in[2];
  const float* b1 = (const float*)d_in[3];
  const float* w2 = (const float*)d_in[4];
  const float* b2 = (const float*)d_in[5];
  float* out = (float*)d_out;

  const int N = in_sizes[0] / 128;
  const int E = in_sizes[1] / 2;
  const int* erow = ei;
  const int* ecol = ei + E;
  const int NB = CDIV(N, 256);

  // workspace carve (256B aligned)
  char* p = (char*)d_ws;
  auto carve = [&](size_t bytes) { void* r = (void*)p; p += (bytes + 255) & ~(size_t)255; return r; };
  int*            cnt  = (int*)carve((size_t)N * 4);
  float*          dinv = (float*)carve((size_t)N * 4);
  float*          rdeg = (float*)carve((size_t)N * 4);
  int*            off  = (int*)carve((size_t)(N + 1) * 4);
  int*            cur  = (int*)carve((size_t)N * 4);
  int*            bsum = (int*)carve(1024 * 4);
  int*            boff = (int*)carve(1024 * 4);
  int*            rows = (int*)carve((size_t)E * 4);
  unsigned short* s0b  = (unsigned short*)carve((size_t)N * 128 * 2);
  unsigned short* s1b  = (unsigned short*)carve((size_t)N * 128 * 2);
  unsigned short* s2b  = (unsigned short*)carve((size_t)N * 128 * 2);
  float*          t1s  = (float*)carve((size_t)N * 40 * 4);
  unsigned short* w1t  = (unsigned short*)carve((size_t)3 * 512 * 128 * 2);
  unsigned short* w2t  = (unsigned short*)carve((size_t)80 * 1536 * 2);
  float*          u1   = (float*)s2b;   // s2b dead after chunk loop

  // Hb chunk rows: fit workspace AND stay L3-resident (<= 32768 rows = 96 MB)
  size_t usedB = (size_t)(p - (char*)d_ws);
  size_t remB  = (ws_size > usedB + (1u << 20)) ? (ws_size - usedB - (1u << 20)) : 0;
  long long cap = (long long)(remB / (1536 * 2));
  int Cmax = (cap >= (long long)N) ? N : (int)cap;
  if (Cmax > 32768) Cmax = 32768;
  Cmax &= ~255;
  if (Cmax < 256) Cmax = 256;
  unsigned short* Hb = (unsigned short*)carve((size_t)Cmax * 1536 * 2);

  // weights -> bf16
  k_w1t<<<CDIV(3 * 512 * 128, 256), 256, 0, stream>>>(w1, w1t);
  k_w2t<<<CDIV(80 * 1536, 256), 256, 0, stream>>>(w2, w2t);

  // degrees + CSR build (sorted by destination col)
  k_zero<<<CDIV(N, 256), 256, 0, stream>>>(cnt, N);
  k_cnt<<<CDIV(E, 256), 256, 0, stream>>>(ecol, cnt, E);
  k_dinv<<<CDIV(N, 256), 256, 0, stream>>>(cnt, dinv, rdeg, N);
  k_scan1<<<NB, 256, 0, stream>>>(cnt, off, bsum, N);
  k_scan2<<<1, 1024, 0, stream>>>(bsum, boff, off, NB, N);
  k_scan3<<<CDIV(N, 256), 256, 0, stream>>>(off, boff, cur, N);
  k_scatter<<<CDIV(E, 256), 256, 0, stream>>>(erow, ecol, cur, rows, E);

  // s0 = dinv ⊙ x (bf16); s1 = dinv^2(s0 + gather); s2 likewise
  k_cvts<<<CDIV(N * 32, 256), 256, 0, stream>>>(x, dinv, s0b, N * 32);
  k_gather128<<<CDIV(N, 4), 256, 0, stream>>>(s0b, off, rows, dinv, s1b, N);
  k_gather128<<<CDIV(N, 4), 256, 0, stream>>>(s1b, off, rows, dinv, s2b, N);

  // chunked: H = relu(rdeg*(s_p @ W1_p) + b1); t0 -> out[:,0:40]+b2; t1s = dinv*(H @ w2[1])
  for (int r0 = 0; r0 < N; r0 += Cmax) {
    int Mc = (N - r0 < Cmax) ? (N - r0) : Cmax;
    int g1 = CDIV(Mc, 64);
    k_gemm1<<<g1, 256, 0, stream>>>(s0b + (size_t)r0 * 128, w1t,          rdeg + r0, b1, Hb, Mc, 0);
    k_gemm1<<<g1, 256, 0, stream>>>(s1b + (size_t)r0 * 128, w1t +  65536, rdeg + r0, b1, Hb, Mc, 512);
    k_gemm1<<<g1, 256, 0, stream>>>(s2b + (size_t)r0 * 128, w1t + 131072, rdeg + r0, b1, Hb, Mc, 1024);
    k_gemm2<<<CDIV(Mc, 256), 256, 0, stream>>>(Hb, w2t, b2, dinv + r0,
                                               out + (size_t)r0 * 80,
                                               t1s + (size_t)r0 * 40, Mc);
  }

  // u1 = dinv ⊙ (t1s + gather t1s)  (width 40); u1 aliases s2b (dead now)
  k_gather40<<<CDIV(N, 4), 256, 0, stream>>>(t1s, off, rows, dinv, u1, N);

  // out = log_softmax([t0+b2[0:40], u1+b2[40:80]])
  k_logsm<<<CDIV(N, 4), 256, 0, stream>>>(out, u1, b2, N);
}